// Round 1
// baseline (1392.419 us; speedup 1.0000x reference)
//
#include <hip/hip_runtime.h>

// Problem constants
#define B_ 2
#define L_ 4096
#define D_ 512
#define H_ 8
#define DK_ 64
#define DV_ 64
#define M_ 8192          // B*L
#define OUT_ELEMS 524288 // B*L*DV

typedef __attribute__((ext_vector_type(8))) short short8;
typedef __attribute__((ext_vector_type(4))) float f32x4;
typedef __attribute__((ext_vector_type(4))) unsigned short u16x4;

#define MFMA16(a, b, c) __builtin_amdgcn_mfma_f32_16x16x32_bf16((a), (b), (c), 0, 0, 0)

static __device__ __forceinline__ unsigned short f2bf(float f) {
  union { float f; unsigned int u; } v; v.f = f;
  unsigned int u = v.u;
  u += 0x7fffu + ((u >> 16) & 1u);   // round-to-nearest-even
  return (unsigned short)(u >> 16);
}
static __device__ __forceinline__ float b2f(unsigned short s) {
  union { unsigned int u; float f; } v; v.u = ((unsigned int)s) << 16; return v.f;
}
// async global->LDS, 16B per lane; lds base must be wave-uniform (lane i lands at base + i*16)
static __device__ __forceinline__ void gl_lds16(const void* g, void* l) {
  __builtin_amdgcn_global_load_lds(
      (const __attribute__((address_space(1))) unsigned int*)g,
      (__attribute__((address_space(3))) unsigned int*)l, 16, 0, 0);
}

// ---------------------------------------------------------------------------
// fp32 -> bf16 conversion, 3 tensors per launch (blockIdx.y selects)
// ---------------------------------------------------------------------------
__global__ __launch_bounds__(256) void cvt3_kernel(
    const float* __restrict__ s0, const float* __restrict__ s1, const float* __restrict__ s2,
    unsigned short* __restrict__ d0, unsigned short* __restrict__ d1, unsigned short* __restrict__ d2,
    int n4) {
  const float* s = (blockIdx.y == 0) ? s0 : ((blockIdx.y == 1) ? s1 : s2);
  unsigned short* d = (blockIdx.y == 0) ? d0 : ((blockIdx.y == 1) ? d1 : d2);
  int i = blockIdx.x * 256 + threadIdx.x;
  if (i >= n4) return;
  f32x4 f = ((const f32x4*)s)[i];
  u16x4 o;
  o.x = f2bf(f.x); o.y = f2bf(f.y); o.z = f2bf(f.z); o.w = f2bf(f.w);
  ((u16x4*)d)[i] = o;
}

// ---------------------------------------------------------------------------
// Projection / fc GEMM:  Y[m][n] = sum_k xb[m][k] * wb[n][k] + bias[n]
// K = 512 fixed. 64x64 tile per block, 4 waves, wave w owns n-strip [16w,16w+16).
// mode 0: Q -> bf16 [b,h,l,d], scaled by 0.125
// mode 1: K -> bf16 [b,h,l,d]
// mode 2: V -> bf16 [b,h,d,l]   (transposed for PV B-fragments)
// mode 3: fc -> fp32 [m][64]
// ---------------------------------------------------------------------------
__global__ __launch_bounds__(256, 4) void proj_kernel(
    const unsigned short* __restrict__ xb, const unsigned short* __restrict__ wb,
    const float* __restrict__ bias, void* __restrict__ outp, int mode) {
  __shared__ unsigned short As[64 * 64];
  __shared__ unsigned short Bs[64 * 64];
  const int tid = threadIdx.x;
  const int w = tid >> 6, lane = tid & 63;
  const int quad = lane >> 4, l16 = lane & 15;
  const int m0 = blockIdx.x * 64, n0 = blockIdx.y * 64;

  f32x4 acc[4] = {};

  for (int kt = 0; kt < 8; ++kt) {
    const int k0 = kt * 64;
    __syncthreads();
    for (int c = 0; c < 2; ++c) {
      const int row = w * 16 + c * 8 + (lane >> 3);
      const int col = (lane & 7) * 8;
      gl_lds16(xb + (size_t)(m0 + row) * 512 + k0 + col, &As[(w * 16 + c * 8) * 64]);
      gl_lds16(wb + (size_t)(n0 + row) * 512 + k0 + col, &Bs[(w * 16 + c * 8) * 64]);
    }
    __syncthreads();
    for (int ks = 0; ks < 2; ++ks) {
      short8 bfrag = *(const short8*)&Bs[(w * 16 + l16) * 64 + ks * 32 + quad * 8];
      for (int mf = 0; mf < 4; ++mf) {
        short8 afrag = *(const short8*)&As[(mf * 16 + l16) * 64 + ks * 32 + quad * 8];
        acc[mf] = MFMA16(afrag, bfrag, acc[mf]);
      }
    }
  }

  const int n_l = n0 + w * 16 + l16;   // global output column
  const float bv = bias[n_l];
  for (int mf = 0; mf < 4; ++mf) {
    for (int r = 0; r < 4; ++r) {
      const int m = m0 + mf * 16 + quad * 4 + r;
      float v = acc[mf][r] + bv;
      if (mode <= 1) {
        if (mode == 0) v *= 0.125f;   // fold 1/sqrt(DK) into Q
        const int b = m >> 12, l = m & 4095;
        const int h = n_l >> 6, dloc = n_l & 63;
        ((unsigned short*)outp)[(((size_t)(b * H_ + h) * L_ + l) << 6) + dloc] = f2bf(v);
      } else if (mode == 2) {
        const int b = m >> 12, l = m & 4095;
        const int h = n_l >> 6, dloc = n_l & 63;
        ((unsigned short*)outp)[(((size_t)(b * H_ + h) * DV_ + dloc) << 12) + l] = f2bf(v);
      } else {
        ((float*)outp)[(size_t)m * 64 + n_l] = v;
      }
    }
  }
}

// ---------------------------------------------------------------------------
// Fused attention: per (b,h, 64-row Q-tile):
//  pass A: stream K-tiles (128 cols), S = Q K^T (Q pre-scaled), rowsum += exp(S)
//  pass B: recompute S, P = exp(S)/rowsum, P -> LDS (bf16) -> coalesced fp32
//          global write of attn + P.V accumulation -> ctx
// ---------------------------------------------------------------------------
__global__ __launch_bounds__(256, 2) void attn_kernel(
    const unsigned short* __restrict__ Qh, const unsigned short* __restrict__ Kh,
    const unsigned short* __restrict__ Vt, float* __restrict__ attn,
    unsigned short* __restrict__ ctx) {
  __shared__ unsigned short Qs[64 * 64];    // Q tile [q][d]
  __shared__ unsigned short Ks[128 * 64];   // K tile [kcol][d]
  __shared__ unsigned short Vs[64 * 128];   // V tile [dv][kcol] (from transposed Vt)
  __shared__ unsigned short Ps[64 * 136];   // P tile [q][kcol], padded stride

  const int tid = threadIdx.x;
  const int w = tid >> 6, lane = tid & 63;
  const int quad = lane >> 4, l16 = lane & 15;
  const int q0 = blockIdx.x * 64;
  const int bh = blockIdx.y;            // b*H + h
  const int b = bh >> 3, h = bh & 7;

  const unsigned short* Qp = Qh + (size_t)bh * L_ * 64;
  const unsigned short* Kp = Kh + (size_t)bh * L_ * 64;
  const unsigned short* Vp = Vt + (size_t)bh * 64 * L_;
  float* attnp = attn + ((size_t)(h * B_ + b) * L_ + q0) * L_;  // attn_view [h,b,q,k]

  // stage Q tile once; Q stays in registers for the whole kernel
  for (int c = 0; c < 2; ++c) {
    const int row = w * 16 + c * 8 + (lane >> 3);
    gl_lds16(Qp + (size_t)(q0 + row) * 64 + (lane & 7) * 8, &Qs[(w * 16 + c * 8) * 64]);
  }
  __syncthreads();
  short8 qa0 = *(const short8*)&Qs[(w * 16 + l16) * 64 + quad * 8];
  short8 qa1 = *(const short8*)&Qs[(w * 16 + l16) * 64 + 32 + quad * 8];

  // ---- pass A: row sums of exp(S) ----
  float rs0 = 0.f, rs1 = 0.f, rs2 = 0.f, rs3 = 0.f;
  for (int t = 0; t < 32; ++t) {
    __syncthreads();
    for (int c = 0; c < 4; ++c) {
      const int row = w * 32 + c * 8 + (lane >> 3);
      gl_lds16(Kp + (size_t)(t * 128 + row) * 64 + (lane & 7) * 8, &Ks[(w * 32 + c * 8) * 64]);
    }
    __syncthreads();
    for (int nf = 0; nf < 8; ++nf) {
      f32x4 s = {};
      short8 kb0 = *(const short8*)&Ks[(nf * 16 + l16) * 64 + quad * 8];
      short8 kb1 = *(const short8*)&Ks[(nf * 16 + l16) * 64 + 32 + quad * 8];
      s = MFMA16(qa0, kb0, s);
      s = MFMA16(qa1, kb1, s);
      rs0 += __expf(s[0]); rs1 += __expf(s[1]);
      rs2 += __expf(s[2]); rs3 += __expf(s[3]);
    }
  }
  // butterfly across the 16 lanes sharing a row-quad -> every lane gets full sum
  for (int m = 1; m < 16; m <<= 1) {
    rs0 += __shfl_xor(rs0, m, 64); rs1 += __shfl_xor(rs1, m, 64);
    rs2 += __shfl_xor(rs2, m, 64); rs3 += __shfl_xor(rs3, m, 64);
  }
  float inv[4];
  inv[0] = 1.0f / rs0; inv[1] = 1.0f / rs1; inv[2] = 1.0f / rs2; inv[3] = 1.0f / rs3;

  // ---- pass B: recompute, normalize, write attn, accumulate P.V ----
  f32x4 oacc[4] = {};
  for (int t = 0; t < 32; ++t) {
    __syncthreads();
    for (int c = 0; c < 4; ++c) {
      const int row = w * 32 + c * 8 + (lane >> 3);
      gl_lds16(Kp + (size_t)(t * 128 + row) * 64 + (lane & 7) * 8, &Ks[(w * 32 + c * 8) * 64]);
    }
    for (int c = 0; c < 4; ++c) {
      const int row = w * 16 + c * 4 + (lane >> 4);
      gl_lds16(Vp + (size_t)row * L_ + t * 128 + (lane & 15) * 8, &Vs[(w * 16 + c * 4) * 128]);
    }
    __syncthreads();
    for (int nf = 0; nf < 8; ++nf) {
      f32x4 s = {};
      short8 kb0 = *(const short8*)&Ks[(nf * 16 + l16) * 64 + quad * 8];
      short8 kb1 = *(const short8*)&Ks[(nf * 16 + l16) * 64 + 32 + quad * 8];
      s = MFMA16(qa0, kb0, s);
      s = MFMA16(qa1, kb1, s);
      for (int r = 0; r < 4; ++r) {
        float p = __expf(s[r]) * inv[r];
        Ps[(w * 16 + quad * 4 + r) * 136 + nf * 16 + l16] = f2bf(p);
      }
    }
    __syncthreads();
    // coalesced fp32 attn write: 2 full 512B rows per wave-instruction
    {
      const int rbase = tid >> 5;          // 0..7
      const int cb = (tid & 31) * 4;       // 0..124
      for (int it = 0; it < 8; ++it) {
        const int row = it * 8 + rbase;
        u16x4 pv = *(const u16x4*)&Ps[row * 136 + cb];
        f32x4 val;
        val.x = b2f(pv.x); val.y = b2f(pv.y); val.z = b2f(pv.z); val.w = b2f(pv.w);
        *(f32x4*)(attnp + (size_t)row * L_ + t * 128 + cb) = val;
      }
    }
    // P.V: A-frags from own wave's Ps rows, B-frags from Vs
    for (int ks = 0; ks < 4; ++ks) {
      short8 pa = *(const short8*)&Ps[(w * 16 + l16) * 136 + ks * 32 + quad * 8];
      for (int nf = 0; nf < 4; ++nf) {
        short8 vb = *(const short8*)&Vs[(nf * 16 + l16) * 128 + ks * 32 + quad * 8];
        oacc[nf] = MFMA16(pa, vb, oacc[nf]);
      }
    }
  }

  // ctx [b, l, h*64 + dv] bf16
  for (int nf = 0; nf < 4; ++nf) {
    for (int r = 0; r < 4; ++r) {
      const int q = q0 + w * 16 + quad * 4 + r;
      const int col = h * 64 + nf * 16 + l16;
      ctx[(size_t)(b * L_ + q) * 512 + col] = f2bf(oacc[nf][r]);
    }
  }
}

// ---------------------------------------------------------------------------
extern "C" void kernel_launch(void* const* d_in, const int* in_sizes, int n_in,
                              void* d_out, int out_size, void* d_ws, size_t ws_size,
                              hipStream_t stream) {
  const float* q    = (const float*)d_in[0];
  const float* k    = (const float*)d_in[1];
  const float* v    = (const float*)d_in[2];
  const float* wq   = (const float*)d_in[3];
  const float* bq   = (const float*)d_in[4];
  const float* wk   = (const float*)d_in[5];
  const float* bk   = (const float*)d_in[6];
  const float* wv   = (const float*)d_in[7];
  const float* bv   = (const float*)d_in[8];
  const float* fcw  = (const float*)d_in[9];
  const float* fcb  = (const float*)d_in[10];

  float* outp  = (float*)d_out;
  float* attnp = outp + OUT_ELEMS;

  // workspace layout (bf16 arrays), ~60.4 MB total
  unsigned short* qb   = (unsigned short*)d_ws;
  unsigned short* kb   = qb + (size_t)M_ * D_;
  unsigned short* vb   = kb + (size_t)M_ * D_;
  unsigned short* wqb  = vb + (size_t)M_ * D_;
  unsigned short* wkb  = wqb + 512 * 512;
  unsigned short* wvb  = wkb + 512 * 512;
  unsigned short* fcwb = wvb + 512 * 512;
  unsigned short* Qh   = fcwb + 64 * 512;
  unsigned short* Kh   = Qh + (size_t)M_ * D_;
  unsigned short* Vt   = Kh + (size_t)M_ * D_;
  unsigned short* ctx  = Vt + (size_t)M_ * D_;

  cvt3_kernel<<<dim3(4096, 3), 256, 0, stream>>>(q, k, v, qb, kb, vb, (M_ * D_) / 4);
  cvt3_kernel<<<dim3(256, 3), 256, 0, stream>>>(wq, wk, wv, wqb, wkb, wvb, (512 * 512) / 4);
  cvt3_kernel<<<dim3(32, 1), 256, 0, stream>>>(fcw, fcw, fcw, fcwb, fcwb, fcwb, (64 * 512) / 4);

  proj_kernel<<<dim3(128, 8), 256, 0, stream>>>(qb, wqb, bq, Qh, 0);
  proj_kernel<<<dim3(128, 8), 256, 0, stream>>>(kb, wkb, bk, Kh, 1);
  proj_kernel<<<dim3(128, 8), 256, 0, stream>>>(vb, wvb, bv, Vt, 2);

  attn_kernel<<<dim3(64, 16), 256, 0, stream>>>(Qh, Kh, Vt, attnp, ctx);

  proj_kernel<<<dim3(128, 1), 256, 0, stream>>>(ctx, fcwb, fcb, outp, 3);
}